// Round 9
// baseline (532.110 us; speedup 1.0000x reference)
//
#include <hip/hip_runtime.h>
#include <hip/hip_bf16.h>
#include <cstddef>

// GPT-2 block. B=4 (derived), S=2048, D=1024, H=16, DH=64, FF=4096.
#define SEQ   2048
#define DMODEL 1024
#define NHEAD 16
#define HDIM  64
#define FFDIM 4096
#define QT    (SEQ / 64)   // 32 q-tiles

typedef __attribute__((ext_vector_type(8))) short bf16x8;
typedef __attribute__((ext_vector_type(4))) short bf16x4;
typedef __attribute__((ext_vector_type(4))) float f32x4;

#define QSCALE (0.125f * 1.44269504088896f)  // 1/sqrt(64) * log2(e)

__device__ __forceinline__ unsigned short f2b(float x) {
  __hip_bfloat16 h = __float2bfloat16(x);
  return __builtin_bit_cast(unsigned short, h);
}
__device__ __forceinline__ float b2f(short u) {
  unsigned x = ((unsigned)(unsigned short)u) << 16;
  return __builtin_bit_cast(float, x);
}
// async global->LDS, 16B per lane. LDS dest = wave-uniform base + lane*16.
__device__ __forceinline__ void gl16(const short* g, short* l) {
  __builtin_amdgcn_global_load_lds(
      (const __attribute__((address_space(1))) void*)g,
      (__attribute__((address_space(3))) void*)l, 16, 0, 0);
}

// ---------------------------------------------------------------------------
// LayerNorm: one block per row, 256 threads, float4/thread; bf16 output.
// ---------------------------------------------------------------------------
__global__ __launch_bounds__(256)
void ln_kernel(const float* __restrict__ x, const float* __restrict__ g,
               const float* __restrict__ b, short* __restrict__ y) {
  const int row = blockIdx.x;
  const int t = threadIdx.x;
  const float* xr = x + (size_t)row * DMODEL;
  float4 v = *(const float4*)(xr + t * 4);
  float s = v.x + v.y + v.z + v.w;
  float q = v.x * v.x + v.y * v.y + v.z * v.z + v.w * v.w;
  #pragma unroll
  for (int off = 32; off; off >>= 1) {
    s += __shfl_xor(s, off);
    q += __shfl_xor(q, off);
  }
  __shared__ float ss[4], qq[4];
  if ((t & 63) == 0) { ss[t >> 6] = s; qq[t >> 6] = q; }
  __syncthreads();
  s = ss[0] + ss[1] + ss[2] + ss[3];
  q = qq[0] + qq[1] + qq[2] + qq[3];
  const float mean = s * (1.f / DMODEL);
  const float var = q * (1.f / DMODEL) - mean * mean;
  const float rstd = rsqrtf(var + 1e-5f);
  float4 gv = *(const float4*)(g + t * 4);
  float4 bv = *(const float4*)(b + t * 4);
  bf16x4 o;
  o[0] = (short)f2b((v.x - mean) * rstd * gv.x + bv.x);
  o[1] = (short)f2b((v.y - mean) * rstd * gv.y + bv.y);
  o[2] = (short)f2b((v.z - mean) * rstd * gv.z + bv.z);
  o[3] = (short)f2b((v.w - mean) * rstd * gv.w + bv.w);
  *(bf16x4*)(y + (size_t)row * DMODEL + t * 4) = o;
}

// ---------------------------------------------------------------------------
// GELU (GPT-2 'gelu_new')
// ---------------------------------------------------------------------------
__device__ __forceinline__ float gelu_new_f(float x) {
  const float c = 0.7978845608028654f;  // sqrt(2/pi)
  float u = c * (x + 0.044715f * x * x * x);
  float e = __expf(2.f * u);
  float t = 1.f - 2.f / (e + 1.f);
  return 0.5f * x * (1.f + t);
}

// ---------------------------------------------------------------------------
// Fused weight convert+transpose (fp32 [K][N] -> bf16 [N][K]) for 4 weights.
// Q-columns (n<1024) of w_attn pre-scaled by QSCALE. Block 3072 scales b_attn.
// ---------------------------------------------------------------------------
__global__ __launch_bounds__(256)
void wconv4_kernel(const float* __restrict__ w0, short* __restrict__ t0,
                   const float* __restrict__ w1, short* __restrict__ t1,
                   const float* __restrict__ w2, short* __restrict__ t2,
                   const float* __restrict__ w3, short* __restrict__ t3,
                   const float* __restrict__ ba, float* __restrict__ bas) {
  int id = blockIdx.x;
  const int t = threadIdx.x;
  if (id == 3072) {  // bias pre-scale for the QKV GEMM
    #pragma unroll
    for (int i = t; i < 3072; i += 256)
      bas[i] = ba[i] * (i < 1024 ? QSCALE : 1.f);
    return;
  }
  const float* W; short* Wt; int K, N;
  float sc = 1.f;
  if (id < 768)       { W = w0; Wt = t0; K = 1024; N = 3072; }
  else if (id < 1024) { id -= 768;  W = w1; Wt = t1; K = 1024; N = 1024; }
  else if (id < 2048) { id -= 1024; W = w2; Wt = t2; K = 1024; N = 4096; }
  else                { id -= 2048; W = w3; Wt = t3; K = 4096; N = 1024; }
  const int nt = N >> 6;
  const int n0 = (id % nt) * 64, k0 = (id / nt) * 64;
  if (W == w0 && n0 < 1024) sc = QSCALE;  // Q column block
  __shared__ short tile[64][72];
  #pragma unroll
  for (int i = 0; i < 4; ++i) {
    const int row = i * 16 + (t >> 4);      // k within tile
    const int col4 = (t & 15) * 4;          // n within tile
    float4 v = *(const float4*)(W + (size_t)(k0 + row) * N + n0 + col4);
    tile[col4 + 0][row] = (short)f2b(v.x * sc);
    tile[col4 + 1][row] = (short)f2b(v.y * sc);
    tile[col4 + 2][row] = (short)f2b(v.z * sc);
    tile[col4 + 3][row] = (short)f2b(v.w * sc);
  }
  __syncthreads();
  #pragma unroll
  for (int i = 0; i < 2; ++i) {
    const int cc = t + i * 256;
    const int nr = cc >> 3, k8 = (cc & 7) * 8;
    bf16x8 vv;
    #pragma unroll
    for (int j = 0; j < 8; ++j) vv[j] = tile[nr][k8 + j];
    *(bf16x8*)(Wt + (size_t)(n0 + nr) * K + k0 + k8) = vv;
  }
}

// ---------------------------------------------------------------------------
// bf16 MFMA GEMM: C[M,N] = A[M,K](bf16) @ Bt[N,K](bf16)^T + bias (+R fp32)
// 128x128 tile, BK=32, 4 waves, mfma_f32_16x16x32_bf16.
// DEPTH-2 PIPELINE (T3+T4): 3 LDS buffers (48KB -> 3 blocks/CU); stage tile
// kt+2 while computing kt; raw `s_waitcnt vmcnt(4); s_barrier` per iter
// (never 0 mid-loop): in-flight = {T(t+1):4, T(t+2):4}; vmcnt(4) forces the
// older 4 (T(t+1)) complete, leaves T(t+2) flying across the barrier.
// Each wave waits its OWN loads; barrier then globalizes. WAR on recycled
// buffer ordered by the previous barrier. LDS rows 64B, XOR swizzle
// byte ^= ((row>>1)&3)<<4 (<=2-way conflicts = free), pre-swizzled source.
// T5 setprio around the MFMA cluster. T1 XCD swizzle on a 1-D grid.
// QKVS: epilogue scatters Q/K/V to per-head [b][h][s][64] (C,C2,C3).
// ---------------------------------------------------------------------------
template <bool OUTBF, bool GELU, bool RES, bool QKVS>
__global__ __launch_bounds__(256)
void gemm_bf16(const short* __restrict__ A, const short* __restrict__ Bt,
               const float* __restrict__ bias, const float* __restrict__ R,
               void* __restrict__ C, short* __restrict__ C2,
               short* __restrict__ C3, int M, int N, int K, int nbn) {
  __shared__ short As[3][128 * 32];
  __shared__ short Bs[3][128 * 32];
  const int t = threadIdx.x, lane = t & 63, w = t >> 6;
  const int g = lane >> 4, la = lane & 15;
  // XCD swizzle: consecutive swz ids land on one XCD -> A-panel L2 locality
  const int cpx = gridDim.x >> 3;
  const int swz = (blockIdx.x & 7) * cpx + (blockIdx.x >> 3);
  const int bn = swz % nbn, bm = swz / nbn;
  const int wm = w >> 1, wn = w & 1;

  // staging: chunk c in {t, t+256}; row=c>>2 (0..127), col16=c&3; LDS linear
  // byte c*16; source k pre-swizzled so linear LDS == swizzled layout.
  const int r0 = t >> 2;                      // rows r0 and r0+64
  const int sca = ((t & 3) ^ ((r0 >> 1) & 3)) * 8;  // element offset in k
  const short* Ag0 = A + (size_t)(bm * 128 + r0) * K + sca;
  const short* Ag1 = A + (size_t)(bm * 128 + r0 + 64) * K + sca;
  const short* Bg0 = Bt + (size_t)(bn * 128 + r0) * K + sca;
  const short* Bg1 = Bt + (size_t)(bn * 128 + r0 + 64) * K + sca;

  f32x4 acc[4][4];
  #pragma unroll
  for (int i = 0; i < 4; ++i)
    #pragma unroll
    for (int j = 0; j < 4; ++j) acc[i][j] = (f32x4){0.f, 0.f, 0.f, 0.f};

  const int KT = K >> 5;
  #define STAGE_G(buf, kt)                                   \
    do {                                                     \
      gl16(Ag0 + (kt) * 32, As[buf] + t * 8);                \
      gl16(Ag1 + (kt) * 32, As[buf] + 2048 + t * 8);         \
      gl16(Bg0 + (kt) * 32, Bs[buf] + t * 8);                \
      gl16(Bg1 + (kt) * 32, Bs[buf] + 2048 + t * 8);         \
    } while (0)

  // prologue: stage T0,T1; wait T0 (allow T1's 4 in flight); barrier.
  STAGE_G(0, 0);
  STAGE_G(1, 1);
  asm volatile("s_waitcnt vmcnt(4)\n\ts_barrier" ::: "memory");
  __builtin_amdgcn_sched_barrier(0);

  int bcur = 0;
  #pragma unroll 1
  for (int kt = 0; kt < KT; ++kt) {
    if (kt + 2 < KT) {
      const int btgt = bcur == 0 ? 2 : bcur - 1;  // (bcur+2)%3
      STAGE_G(btgt, kt + 2);
    }
    bf16x8 af[4], bfr[4];
    #pragma unroll
    for (int mi = 0; mi < 4; ++mi) {
      const int row = wm * 64 + mi * 16 + la;
      af[mi] = *(const bf16x8*)((const char*)As[bcur] + row * 64 +
                                ((g ^ ((row >> 1) & 3)) << 4));
    }
    #pragma unroll
    for (int ni = 0; ni < 4; ++ni) {
      const int row = wn * 64 + ni * 16 + la;
      bfr[ni] = *(const bf16x8*)((const char*)Bs[bcur] + row * 64 +
                                 ((g ^ ((row >> 1) & 3)) << 4));
    }
    __builtin_amdgcn_s_setprio(1);
    #pragma unroll
    for (int mi = 0; mi < 4; ++mi)
      #pragma unroll
      for (int ni = 0; ni < 4; ++ni)
        acc[mi][ni] = __builtin_amdgcn_mfma_f32_16x16x32_bf16(
            af[mi], bfr[ni], acc[mi][ni], 0, 0, 0);
    __builtin_amdgcn_s_setprio(0);

    if (kt < KT - 2) {
      asm volatile("s_waitcnt vmcnt(4)\n\ts_barrier" ::: "memory");
    } else if (kt == KT - 2) {
      asm volatile("s_waitcnt vmcnt(0)\n\ts_barrier" ::: "memory");
    }
    __builtin_amdgcn_sched_barrier(0);
    bcur = bcur == 2 ? 0 : bcur + 1;
  }
  #undef STAGE_G

  const int crow0 = bm * 128 + wm * 64 + g * 4;
  const int ccol0 = bn * 128 + wn * 64 + la;
  float bl[4];
  #pragma unroll
  for (int ni = 0; ni < 4; ++ni) bl[ni] = bias[ccol0 + ni * 16];
  #pragma unroll
  for (int mi = 0; mi < 4; ++mi) {
    #pragma unroll
    for (int r = 0; r < 4; ++r) {
      const int row = crow0 + mi * 16 + r;
      if (QKVS) {
        const int bq = row >> 11, s = row & 2047;   // SEQ=2048
        #pragma unroll
        for (int ni = 0; ni < 4; ++ni) {
          const int n = ccol0 + ni * 16;
          const int region = n >> 10;               // 0=Q 1=K 2=V
          const int nn = n & 1023;
          short* dst = region == 0 ? (short*)C : (region == 1 ? C2 : C3);
          dst[((size_t)(bq * NHEAD + (nn >> 6)) * SEQ + s) * 64 + (nn & 63)] =
              (short)f2b(acc[mi][ni][r] + bl[ni]);
        }
      } else {
        #pragma unroll
        for (int ni = 0; ni < 4; ++ni) {
          float v = acc[mi][ni][r] + bl[ni];
          if (GELU) v = gelu_new_f(v);
          if (RES) v += R[(size_t)row * N + ccol0 + ni * 16];
          if (OUTBF)
            ((short*)C)[(size_t)row * N + ccol0 + ni * 16] = (short)f2b(v);
          else
            ((float*)C)[(size_t)row * N + ccol0 + ni * 16] = v;
        }
      }
    }
  }
}

// ---------------------------------------------------------------------------
// V transpose: Vb bf16 [b][h][s][64] -> Vtb bf16 [b][h][64][s] (LDS tile).
// ---------------------------------------------------------------------------
__global__ __launch_bounds__(256)
void prepv_kernel(const short* __restrict__ Vb, short* __restrict__ Vtb) {
  const int st = blockIdx.x, h = blockIdx.y, b = blockIdx.z;
  const int t = threadIdx.x;
  const int s0 = st * 64;
  const size_t bh = (size_t)b * NHEAD + h;
  __shared__ short vt[64][72];
  #pragma unroll
  for (int i = 0; i < 2; ++i) {
    const int cc = t + i * 256;
    const int r = cc >> 3, d8 = (cc & 7) * 8;
    bf16x8 v8 = *(const bf16x8*)(Vb + (bh * SEQ + s0 + r) * 64 + d8);
    #pragma unroll
    for (int j = 0; j < 8; ++j) vt[d8 + j][r] = v8[j];
  }
  __syncthreads();
  #pragma unroll
  for (int i = 0; i < 2; ++i) {
    const int cc = t + i * 256;
    const int d = cc >> 3, s8 = (cc & 7) * 8;
    bf16x8 vv;
    #pragma unroll
    for (int j = 0; j < 8; ++j) vv[j] = vt[d][s8 + j];
    *(bf16x8*)(Vtb + (bh * 64 + d) * SEQ + s0 + s8) = vv;
  }
}

// ---------------------------------------------------------------------------
// bf16 MFMA causal flash attention (validated R7/R8): paired q-tiles,
// double-buffered staging, log2-domain softmax, defer-max, setprio.
// ---------------------------------------------------------------------------
__global__ __launch_bounds__(256)
void mha_kernel(const short* __restrict__ Qb, const short* __restrict__ Kb,
                const short* __restrict__ Vtb, short* __restrict__ out) {
  const int p = blockIdx.x, h = blockIdx.y, b = blockIdx.z;
  const int t = threadIdx.x, lane = t & 63, w = t >> 6;
  const int g = lane >> 4, la = lane & 15;
  const size_t bh = (size_t)b * NHEAD + h;

  __shared__ short Ks[2][64 * 64];
  __shared__ short Vts[2][64 * 64];
  __shared__ short Ps[4][16 * 64];

  const int srow = t >> 3;
  const int scolb = ((t & 7) * 16) ^ ((srow & 7) << 4);  // pre-swizzled

  const int qt0 = p, qt1 = QT - 1 - p;
  const int T0 = qt0 + 1, total = T0 + qt1 + 1;

  int qt = qt0;
  const short* qr = Qb + (bh * SEQ + (size_t)qt0 * 64 + w * 16 + la) * 64;
  bf16x8 qf0 = *(const bf16x8*)(qr + g * 8);
  bf16x8 qf1 = *(const bf16x8*)(qr + 32 + g * 8);

  float o[16];
  #pragma unroll
  for (int i = 0; i < 16; ++i) o[i] = 0.f;
  float m = -1e30f, l = 0.f;

  // prologue: stage tile it=0 (k0=0) into buf 0
  #pragma unroll
  for (int i = 0; i < 2; ++i) {
    const int r = srow + i * 32;
    gl16(Kb + (bh * SEQ + r) * 64 + (scolb >> 1), Ks[0] + i * 2048 + t * 8);
    gl16(Vtb + (bh * 64 + r) * SEQ + (scolb >> 1), Vts[0] + i * 2048 + t * 8);
  }
  __syncthreads();  // vmcnt(0) drain: tile 0 resident

  int cur = 0;
  #pragma unroll 1
  for (int it = 0; it < total; ++it) {
    // issue next tile's staging early (hidden under QK/softmax/PV)
    if (it + 1 < total) {
      const int nkt = (it + 1 < T0) ? (it + 1) : (it + 1 - T0);
      const int nk0 = nkt * 64;
      #pragma unroll
      for (int i = 0; i < 2; ++i) {
        const int r = srow + i * 32;
        gl16(Kb + (bh * SEQ + nk0 + r) * 64 + (scolb >> 1),
             Ks[cur ^ 1] + i * 2048 + t * 8);
        gl16(Vtb + (bh * 64 + r) * SEQ + nk0 + (scolb >> 1),
             Vts[cur ^ 1] + i * 2048 + t * 8);
      }
    }

    // === QK^T on buf[cur] ===
    float sv[16];
    __builtin_amdgcn_s_setprio(1);
    #pragma unroll
    for (int mt = 0; mt < 4; ++mt) {
      const int ar = mt * 16 + la;
      const int ab = ar * 128 + ((g * 16) ^ ((ar & 7) << 4));
      bf16x8 ka0 = *(const bf16x8*)((char*)Ks[cur] + ab);
      bf16x8 ka1 = *(const bf16x8*)((char*)Ks[cur] + (ab ^ 64));
      f32x4 sa = {0.f, 0.f, 0.f, 0.f};
      sa = __builtin_amdgcn_mfma_f32_16x16x32_bf16(ka0, qf0, sa, 0, 0, 0);
      sa = __builtin_amdgcn_mfma_f32_16x16x32_bf16(ka1, qf1, sa, 0, 0, 0);
      sv[mt * 4 + 0] = sa[0]; sv[mt * 4 + 1] = sa[1];
      sv[mt * 4 + 2] = sa[2]; sv[mt * 4 + 3] = sa[3];
    }
    __builtin_amdgcn_s_setprio(0);

    const bool diag = (it == T0 - 1) || (it == total - 1);
    if (diag) {  // causal mask (log2 domain: -10000*log2e)
      const int qrel = w * 16 + la;
      #pragma unroll
      for (int idx = 0; idx < 16; ++idx) {
        const int krel = (idx >> 2) * 16 + g * 4 + (idx & 3);
        if (krel > qrel) sv[idx] = -14426.950408889634f;
      }
    }

    // tree max over 16, then cross-g (lanes share la -> per-q-row max)
    float t8[8], t4[4], t2[2];
    #pragma unroll
    for (int i = 0; i < 8; ++i) t8[i] = fmaxf(sv[2 * i], sv[2 * i + 1]);
    #pragma unroll
    for (int i = 0; i < 4; ++i) t4[i] = fmaxf(t8[2 * i], t8[2 * i + 1]);
    t2[0] = fmaxf(t4[0], t4[1]); t2[1] = fmaxf(t4[2], t4[3]);
    float tmax = fmaxf(t2[0], t2[1]);
    tmax = fmaxf(tmax, __shfl_xor(tmax, 16));
    tmax = fmaxf(tmax, __shfl_xor(tmax, 32));

    const bool skip = __all(tmax <= m + 11.5f) != 0;  // defer-max (T13)
    const float mn = skip ? m : fmaxf(m, tmax);

    float ss8[8], ss4[4];
    #pragma unroll
    for (int i = 0; i < 16; ++i) sv[i] = exp2f(sv[i] - mn);
    #pragma unroll
    for (int i = 0; i < 8; ++i) ss8[i] = sv[2 * i] + sv[2 * i + 1];
    #pragma unroll
    for (int i = 0; i < 4; ++i) ss4[i] = ss8[2 * i] + ss8[2 * i + 1];
    float ps = (ss4[0] + ss4[1]) + (ss4[2] + ss4[3]);
    ps += __shfl_xor(ps, 16);
    ps += __shfl_xor(ps, 32);

    if (skip) {
      l += ps;
    } else {
      const float sc = exp2f(m - mn);
      l = l * sc + ps;
      m = mn;
      #pragma unroll
      for (int r = 0; r < 4; ++r) {
        const float scr = __shfl(sc, (g << 2) + r);
        o[r] *= scr; o[4 + r] *= scr; o[8 + r] *= scr; o[12 + r] *= scr;
      }
    }

    // write P (bf16) to per-wave swizzled LDS
    #pragma unroll
    for (int mt = 0; mt < 4; ++mt) {
      #pragma unroll
      for (int r2 = 0; r2 < 2; ++r2) {
        const unsigned pk = (unsigned)f2b(sv[mt * 4 + r2 * 2]) |
                            ((unsigned)f2b(sv[mt * 4 + r2 * 2 + 1]) << 16);
        const int kk = mt * 16 + g * 4 + r2 * 2;
        const int pb = la * 128 + ((kk * 2) ^ ((la & 7) << 4));
        *(unsigned*)((char*)Ps[w] + pb) = pk;
      }
    }
    // same-wave cross-lane LDS RAW hazard: drain + pin (rule #18);
    // gl16 staging uses vmcnt, NOT lgkmcnt -> stays in flight.
    asm volatile("s_waitcnt lgkmcnt(0)" ::: "memory");
    __builtin_amdgcn_sched_barrier(0);

    const int pb0 = la * 128 + ((g * 16) ^ ((la & 7) << 4));
    const bf16x8 pa0 = *(const bf16x8*)((char*)Ps[w] + pb0);
    const bf16x8 pa1 = *(const bf16x8*)((char*)Ps[w] + (pb0 ^ 64));
    __builtin_amdgcn_s_setprio(1);
    #pragma unroll
    for (int nt = 0; nt < 4; ++nt) {
      const int dr = nt * 16 + la;
      const int vb = dr * 128 + ((g * 16) ^ ((dr & 7) << 4));
      bf16x8 vb0 = *(const bf16x8*)((char*)Vts[cur] + vb);
      bf16x8 vb1 = *(const bf16x8*)((char*)Vts[cur] + (vb ^ 64));
      f32x4 oa = {o[nt * 4 + 0], o[nt * 4 + 1], o[nt * 4 + 2], o[nt * 4 + 3]};
      oa = __builtin_amdgcn_mfma_f32_16x16x32_bf16(pa0, vb0, oa, 0, 0, 0);
      oa = __builtin_amdgcn_mfma_f32_16x16x32_bf16(pa1, vb1, oa, 0, 0, 0);
      o[nt * 4 + 0] = oa[0]; o[nt * 4 + 1] = oa[1];
      o[nt * 4 + 2] = oa[2]; o[nt * 4 + 3] = oa[3];
    }
    __builtin_amdgcn_s_setprio(0);

    if (diag) {  // finished a q-tile: write output (and reset for e=1)
      const float linv = 1.f / l;
      #pragma unroll
      for (int r = 0; r < 4; ++r) {
        const float li = __shfl(linv, (g << 2) + r);
        const int qrow_g = qt * 64 + w * 16 + g * 4 + r;
        #pragma unroll
        for (int nt = 0; nt < 4; ++nt) {
          out[((size_t)b * SEQ + qrow_g) * DMODEL + h * 64 + nt * 16 + la] =
              (short)f2b(o[nt * 4 + r] * li);
        }
      }
      if (it == T0 - 1) {
        #pragma unroll
        for (int i = 0; i < 16; ++i) o[i] = 0.f;
        m = -1e30f; l = 0.f;
        qt = qt1;
        const short* qr1 = Qb + (bh * SEQ + (size_t)qt1 * 64 + w * 16 + la) * 64;
        qf0 = *(const bf16x8*)(qr1 + g * 8);
        qf1 = *(const bf16x8*)(qr1 + 32 + g * 8);
      }
    }

    __syncthreads();  // vmcnt(0)+lgkmcnt(0): next tile resident, reads done
    cur ^= 1;
  }
}

// ---------------------------------------------------------------------------
// Launcher
// ---------------------------------------------------------------------------
extern "C" void kernel_launch(void* const* d_in, const int* in_sizes, int n_in,
                              void* d_out, int out_size, void* d_ws, size_t ws_size,
                              hipStream_t stream) {
  const float* hidden      = (const float*)d_in[0];
  const float* ln1_g       = (const float*)d_in[1];
  const float* ln1_b       = (const float*)d_in[2];
  const float* w_attn      = (const float*)d_in[3];
  const float* b_attn      = (const float*)d_in[4];
  const float* w_attn_proj = (const float*)d_in[5];
  const float* b_attn_proj = (const float*)d_in[6];
  const float* ln2_g       = (const float*)d_in[7];
  const float* ln2_b       = (const float*)d_in[8];
  const float* w_fc        = (const float*)d_in[9];
  const float* b_fc        = (const float*)d_in[10];
  const float* w_mlp_proj  = (const float*)d_in[11];
  const float* b_mlp_proj  = (const float*)d_in[12];
  float* out = (float*)d_out;

  const int Bn = in_sizes[0] / (SEQ * DMODEL);  // batch (=4)
  const int M = Bn * SEQ;                        // 8192 rows

  // Workspace layout (bytes, ~210MB):
  char* W = (char*)d_ws;
  const size_t szMD2 = (size_t)M * DMODEL * 2;        // 16.8MB
  short* xln_b  = (short*)W;                          // LN out
  short* Vb     = (short*)(W + szMD2);                // V [bh][s][64] (attn phase)
  short* a1_b   = Vb;                                 // later: FF acts [M,FF] bf16
  char*  p2     = W + szMD2 + (size_t)M * FFDIM * 2;
  short* Qb     = (short*)p2;
  short* Kb     = Qb + (size_t)M * DMODEL;
  short* Vtb    = Kb + (size_t)M * DMODEL;
  short* attn_b = Vtb + (size_t)M * DMODEL;
  float* h2     = (float*)(p2 + 4 * szMD2);
  short* wat    = (short*)(p2 + 4 * szMD2 + (size_t)M * DMODEL * 4);
  short* wpt    = wat + (size_t)3 * DMODEL * DMODEL;
  short* wft    = wpt + (size_t)DMODEL * DMODEL;
  short* wmt    = wft + (size_t)FFDIM * DMODEL;
  float* bas    = (float*)(wmt + (size_t)DMODEL * FFDIM);  // scaled b_attn

  // 0. fused weight convert+transpose (+ bias prescale block)
  wconv4_kernel<<<3073, 256, 0, stream>>>(w_attn, wat, w_attn_proj, wpt,
                                          w_fc, wft, w_mlp_proj, wmt,
                                          b_attn, bas);
  // 1. LN1 -> bf16
  ln_kernel<<<M, 256, 0, stream>>>(hidden, ln1_g, ln1_b, xln_b);
  // 2. QKV GEMM (1-D grid 24*64=1536), scatter epilogue (Q pre-scaled)
  gemm_bf16<true, false, false, true><<<24 * 64, 256, 0, stream>>>(
      xln_b, wat, bas, nullptr, Qb, Kb, Vb, M, 3 * DMODEL, DMODEL, 24);
  // 2.5 V transpose only
  prepv_kernel<<<dim3(SEQ / 64, NHEAD, Bn), 256, 0, stream>>>(Vb, Vtb);
  // 3. attention -> bf16 [M,1024]  (paired q-tiles, double-buffered)
  mha_kernel<<<dim3(QT / 2, NHEAD, Bn), 256, 0, stream>>>(Qb, Kb, Vtb, attn_b);
  // 4. h2 = hidden + attn @ w_attn_proj + b   (fp32; grid 8*64=512)
  gemm_bf16<false, false, true, false><<<8 * 64, 256, 0, stream>>>(
      attn_b, wpt, b_attn_proj, hidden, h2, nullptr, nullptr, M, DMODEL, DMODEL, 8);
  // 5. LN2 -> bf16
  ln_kernel<<<M, 256, 0, stream>>>(h2, ln2_g, ln2_b, xln_b);
  // 6. a1 = gelu(xln2 @ w_fc + b) -> bf16 [M,4096]  (grid 32*64=2048)
  gemm_bf16<true, true, false, false><<<32 * 64, 256, 0, stream>>>(
      xln_b, wft, b_fc, nullptr, a1_b, nullptr, nullptr, M, FFDIM, DMODEL, 32);
  // 7. out = h2 + a1 @ w_mlp_proj + b  (fp32; grid 8*64=512)
  gemm_bf16<false, false, true, false><<<8 * 64, 256, 0, stream>>>(
      a1_b, wmt, b_mlp_proj, h2, out, nullptr, nullptr, M, DMODEL, FFDIM, 8);
}

// Round 10
// 510.855 us; speedup vs baseline: 1.0416x; 1.0416x over previous
//
#include <hip/hip_runtime.h>
#include <hip/hip_bf16.h>
#include <cstddef>

// GPT-2 block. B=4 (derived), S=2048, D=1024, H=16, DH=64, FF=4096.
#define SEQ   2048
#define DMODEL 1024
#define NHEAD 16
#define HDIM  64
#define FFDIM 4096
#define QT    (SEQ / 64)   // 32 q-tiles

typedef __attribute__((ext_vector_type(8))) short bf16x8;
typedef __attribute__((ext_vector_type(4))) short bf16x4;
typedef __attribute__((ext_vector_type(4))) float f32x4;

#define QSCALE (0.125f * 1.44269504088896f)  // 1/sqrt(64) * log2(e)

__device__ __forceinline__ unsigned short f2b(float x) {
  __hip_bfloat16 h = __float2bfloat16(x);
  return __builtin_bit_cast(unsigned short, h);
}
__device__ __forceinline__ float b2f(short u) {
  unsigned x = ((unsigned)(unsigned short)u) << 16;
  return __builtin_bit_cast(float, x);
}
// async global->LDS, 16B per lane. LDS dest = wave-uniform base + lane*16.
__device__ __forceinline__ void gl16(const short* g, short* l) {
  __builtin_amdgcn_global_load_lds(
      (const __attribute__((address_space(1))) void*)g,
      (__attribute__((address_space(3))) void*)l, 16, 0, 0);
}

// ---------------------------------------------------------------------------
// LayerNorm: one block per row, 256 threads, float4/thread; bf16 output.
// ---------------------------------------------------------------------------
__global__ __launch_bounds__(256)
void ln_kernel(const float* __restrict__ x, const float* __restrict__ g,
               const float* __restrict__ b, short* __restrict__ y) {
  const int row = blockIdx.x;
  const int t = threadIdx.x;
  const float* xr = x + (size_t)row * DMODEL;
  float4 v = *(const float4*)(xr + t * 4);
  float s = v.x + v.y + v.z + v.w;
  float q = v.x * v.x + v.y * v.y + v.z * v.z + v.w * v.w;
  #pragma unroll
  for (int off = 32; off; off >>= 1) {
    s += __shfl_xor(s, off);
    q += __shfl_xor(q, off);
  }
  __shared__ float ss[4], qq[4];
  if ((t & 63) == 0) { ss[t >> 6] = s; qq[t >> 6] = q; }
  __syncthreads();
  s = ss[0] + ss[1] + ss[2] + ss[3];
  q = qq[0] + qq[1] + qq[2] + qq[3];
  const float mean = s * (1.f / DMODEL);
  const float var = q * (1.f / DMODEL) - mean * mean;
  const float rstd = rsqrtf(var + 1e-5f);
  float4 gv = *(const float4*)(g + t * 4);
  float4 bv = *(const float4*)(b + t * 4);
  bf16x4 o;
  o[0] = (short)f2b((v.x - mean) * rstd * gv.x + bv.x);
  o[1] = (short)f2b((v.y - mean) * rstd * gv.y + bv.y);
  o[2] = (short)f2b((v.z - mean) * rstd * gv.z + bv.z);
  o[3] = (short)f2b((v.w - mean) * rstd * gv.w + bv.w);
  *(bf16x4*)(y + (size_t)row * DMODEL + t * 4) = o;
}

// ---------------------------------------------------------------------------
// GELU (GPT-2 'gelu_new')
// ---------------------------------------------------------------------------
__device__ __forceinline__ float gelu_new_f(float x) {
  const float c = 0.7978845608028654f;  // sqrt(2/pi)
  float u = c * (x + 0.044715f * x * x * x);
  float e = __expf(2.f * u);
  float t = 1.f - 2.f / (e + 1.f);
  return 0.5f * x * (1.f + t);
}

// ---------------------------------------------------------------------------
// Fused weight convert+transpose (fp32 [K][N] -> bf16 [N][K]) for 4 weights.
// Q-columns (n<1024) of w_attn pre-scaled by QSCALE. Block 3072 scales b_attn.
// ---------------------------------------------------------------------------
__global__ __launch_bounds__(256)
void wconv4_kernel(const float* __restrict__ w0, short* __restrict__ t0,
                   const float* __restrict__ w1, short* __restrict__ t1,
                   const float* __restrict__ w2, short* __restrict__ t2,
                   const float* __restrict__ w3, short* __restrict__ t3,
                   const float* __restrict__ ba, float* __restrict__ bas) {
  int id = blockIdx.x;
  const int t = threadIdx.x;
  if (id == 3072) {  // bias pre-scale for the QKV GEMM
    #pragma unroll
    for (int i = t; i < 3072; i += 256)
      bas[i] = ba[i] * (i < 1024 ? QSCALE : 1.f);
    return;
  }
  const float* W; short* Wt; int K, N;
  float sc = 1.f;
  if (id < 768)       { W = w0; Wt = t0; K = 1024; N = 3072; }
  else if (id < 1024) { id -= 768;  W = w1; Wt = t1; K = 1024; N = 1024; }
  else if (id < 2048) { id -= 1024; W = w2; Wt = t2; K = 1024; N = 4096; }
  else                { id -= 2048; W = w3; Wt = t3; K = 4096; N = 1024; }
  const int nt = N >> 6;
  const int n0 = (id % nt) * 64, k0 = (id / nt) * 64;
  if (W == w0 && n0 < 1024) sc = QSCALE;  // Q column block
  __shared__ short tile[64][72];
  #pragma unroll
  for (int i = 0; i < 4; ++i) {
    const int row = i * 16 + (t >> 4);      // k within tile
    const int col4 = (t & 15) * 4;          // n within tile
    float4 v = *(const float4*)(W + (size_t)(k0 + row) * N + n0 + col4);
    tile[col4 + 0][row] = (short)f2b(v.x * sc);
    tile[col4 + 1][row] = (short)f2b(v.y * sc);
    tile[col4 + 2][row] = (short)f2b(v.z * sc);
    tile[col4 + 3][row] = (short)f2b(v.w * sc);
  }
  __syncthreads();
  #pragma unroll
  for (int i = 0; i < 2; ++i) {
    const int cc = t + i * 256;
    const int nr = cc >> 3, k8 = (cc & 7) * 8;
    bf16x8 vv;
    #pragma unroll
    for (int j = 0; j < 8; ++j) vv[j] = tile[nr][k8 + j];
    *(bf16x8*)(Wt + (size_t)(n0 + nr) * K + k0 + k8) = vv;
  }
}

// ---------------------------------------------------------------------------
// bf16 MFMA GEMM: C[M,N] = A[M,K](bf16) @ Bt[N,K](bf16)^T + bias (+R fp32)
// 128x128 tile, BK=64, 4 waves, mfma_f32_16x16x32_bf16.
// COUNTED-VMCNT 2-BUFFER PIPELINE (post-R9 revision): keep BK=64 (32 MFMA /
// iter amortization — R9 showed BK=32's doubled per-iter overhead loses),
// but give staging a FULL iteration of latency slack:
//   top:   s_waitcnt vmcnt(8); s_barrier   // T_kt landed; T_{kt+1}'s 8 fly
//   body:  ds_read + 32 MFMA on buf[kt&1]
//   then:  raw s_barrier                   // all waves done reading buf
//   tail:  STAGE(T_{kt+2} -> buf[kt&1])    // consumed 2 barriers later
// vmcnt(8) completes exactly the 8 oldest (= T_kt's); never drains to 0
// mid-loop (T4). Buffer-reuse distance 2 -> 2 buffers suffice (64KB LDS).
// T1 XCD swizzle on 1-D grid; T5 setprio around the MFMA cluster.
// QKVS: epilogue scatters Q/K/V to per-head [b][h][s][64] (C,C2,C3).
// ---------------------------------------------------------------------------
template <bool OUTBF, bool GELU, bool RES, bool QKVS>
__global__ __launch_bounds__(256)
void gemm_bf16(const short* __restrict__ A, const short* __restrict__ Bt,
               const float* __restrict__ bias, const float* __restrict__ R,
               void* __restrict__ C, short* __restrict__ C2,
               short* __restrict__ C3, int M, int N, int K, int nbn) {
  __shared__ short As[2][128 * 64];
  __shared__ short Bs[2][128 * 64];
  const int t = threadIdx.x, lane = t & 63, w = t >> 6;
  const int g = lane >> 4, la = lane & 15;
  // XCD swizzle: consecutive swz ids land on one XCD -> A-panel L2 locality
  const int cpx = gridDim.x >> 3;
  const int swz = (blockIdx.x & 7) * cpx + (blockIdx.x >> 3);
  const int bn = swz % nbn, bm = swz / nbn;
  const int wm = w >> 1, wn = w & 1;

  const int srow = t >> 3;
  const int scolb = ((t & 7) * 16) ^ ((srow & 7) << 4);  // pre-swizzled byte col
  const short* Ag = A + (size_t)(bm * 128 + srow) * K + (scolb >> 1);
  const short* Bg = Bt + (size_t)(bn * 128 + srow) * K + (scolb >> 1);

  f32x4 acc[4][4];
  #pragma unroll
  for (int i = 0; i < 4; ++i)
    #pragma unroll
    for (int j = 0; j < 4; ++j) acc[i][j] = (f32x4){0.f, 0.f, 0.f, 0.f};

  const int KT = K >> 6;
  #define STAGE_G(buf, kt)                                                  \
    do {                                                                    \
      _Pragma("unroll")                                                     \
      for (int i = 0; i < 4; ++i) {                                         \
        gl16(Ag + (size_t)i * 32 * K + (kt) * 64, As[buf] + i * 2048 + t * 8); \
        gl16(Bg + (size_t)i * 32 * K + (kt) * 64, Bs[buf] + i * 2048 + t * 8); \
      }                                                                     \
    } while (0)

  // prologue: 16 loads in flight (T0: 8 older, T1: 8 newer)
  STAGE_G(0, 0);
  STAGE_G(1, 1);

  int cur = 0;
  #pragma unroll 1
  for (int kt = 0; kt < KT; ++kt) {
    // T_kt resident (own 8 oldest), T_{kt+1} stays in flight across barrier
    if (kt + 1 < KT) {
      asm volatile("s_waitcnt vmcnt(8)\n\ts_barrier" ::: "memory");
    } else {
      asm volatile("s_waitcnt vmcnt(0)\n\ts_barrier" ::: "memory");
    }
    __builtin_amdgcn_sched_barrier(0);

    bf16x8 af[4], bfr[4];
    #pragma unroll
    for (int ks = 0; ks < 2; ++ks) {
      #pragma unroll
      for (int mi = 0; mi < 4; ++mi) {
        const int row = wm * 64 + mi * 16 + la;
        af[mi] = *(const bf16x8*)((const char*)As[cur] + row * 128 +
                                  ((ks * 64 + g * 16) ^ ((row & 7) << 4)));
      }
      #pragma unroll
      for (int ni = 0; ni < 4; ++ni) {
        const int row = wn * 64 + ni * 16 + la;
        bfr[ni] = *(const bf16x8*)((const char*)Bs[cur] + row * 128 +
                                   ((ks * 64 + g * 16) ^ ((row & 7) << 4)));
      }
      __builtin_amdgcn_s_setprio(1);
      #pragma unroll
      for (int mi = 0; mi < 4; ++mi)
        #pragma unroll
        for (int ni = 0; ni < 4; ++ni)
          acc[mi][ni] = __builtin_amdgcn_mfma_f32_16x16x32_bf16(
              af[mi], bfr[ni], acc[mi][ni], 0, 0, 0);
      __builtin_amdgcn_s_setprio(0);
    }

    // all waves' ds_reads of buf[cur] complete (consumed by MFMAs) -> safe
    // to restage into it after this raw barrier (no vmcnt drain here!)
    asm volatile("s_barrier" ::: "memory");
    __builtin_amdgcn_sched_barrier(0);
    if (kt + 2 < KT) STAGE_G(cur, kt + 2);
    cur ^= 1;
  }
  #undef STAGE_G

  const int crow0 = bm * 128 + wm * 64 + g * 4;
  const int ccol0 = bn * 128 + wn * 64 + la;
  float bl[4];
  #pragma unroll
  for (int ni = 0; ni < 4; ++ni) bl[ni] = bias[ccol0 + ni * 16];
  #pragma unroll
  for (int mi = 0; mi < 4; ++mi) {
    #pragma unroll
    for (int r = 0; r < 4; ++r) {
      const int row = crow0 + mi * 16 + r;
      if (QKVS) {
        const int bq = row >> 11, s = row & 2047;   // SEQ=2048
        #pragma unroll
        for (int ni = 0; ni < 4; ++ni) {
          const int n = ccol0 + ni * 16;
          const int region = n >> 10;               // 0=Q 1=K 2=V
          const int nn = n & 1023;
          short* dst = region == 0 ? (short*)C : (region == 1 ? C2 : C3);
          dst[((size_t)(bq * NHEAD + (nn >> 6)) * SEQ + s) * 64 + (nn & 63)] =
              (short)f2b(acc[mi][ni][r] + bl[ni]);
        }
      } else {
        #pragma unroll
        for (int ni = 0; ni < 4; ++ni) {
          float v = acc[mi][ni][r] + bl[ni];
          if (GELU) v = gelu_new_f(v);
          if (RES) v += R[(size_t)row * N + ccol0 + ni * 16];
          if (OUTBF)
            ((short*)C)[(size_t)row * N + ccol0 + ni * 16] = (short)f2b(v);
          else
            ((float*)C)[(size_t)row * N + ccol0 + ni * 16] = v;
        }
      }
    }
  }
}

// ---------------------------------------------------------------------------
// V transpose: Vb bf16 [b][h][s][64] -> Vtb bf16 [b][h][64][s] (LDS tile).
// ---------------------------------------------------------------------------
__global__ __launch_bounds__(256)
void prepv_kernel(const short* __restrict__ Vb, short* __restrict__ Vtb) {
  const int st = blockIdx.x, h = blockIdx.y, b = blockIdx.z;
  const int t = threadIdx.x;
  const int s0 = st * 64;
  const size_t bh = (size_t)b * NHEAD + h;
  __shared__ short vt[64][72];
  #pragma unroll
  for (int i = 0; i < 2; ++i) {
    const int cc = t + i * 256;
    const int r = cc >> 3, d8 = (cc & 7) * 8;
    bf16x8 v8 = *(const bf16x8*)(Vb + (bh * SEQ + s0 + r) * 64 + d8);
    #pragma unroll
    for (int j = 0; j < 8; ++j) vt[d8 + j][r] = v8[j];
  }
  __syncthreads();
  #pragma unroll
  for (int i = 0; i < 2; ++i) {
    const int cc = t + i * 256;
    const int d = cc >> 3, s8 = (cc & 7) * 8;
    bf16x8 vv;
    #pragma unroll
    for (int j = 0; j < 8; ++j) vv[j] = vt[d][s8 + j];
    *(bf16x8*)(Vtb + (bh * 64 + d) * SEQ + s0 + s8) = vv;
  }
}

// ---------------------------------------------------------------------------
// bf16 MFMA causal flash attention (validated R7/R8): paired q-tiles,
// double-buffered staging, log2-domain softmax, defer-max, setprio.
// ---------------------------------------------------------------------------
__global__ __launch_bounds__(256)
void mha_kernel(const short* __restrict__ Qb, const short* __restrict__ Kb,
                const short* __restrict__ Vtb, short* __restrict__ out) {
  const int p = blockIdx.x, h = blockIdx.y, b = blockIdx.z;
  const int t = threadIdx.x, lane = t & 63, w = t >> 6;
  const int g = lane >> 4, la = lane & 15;
  const size_t bh = (size_t)b * NHEAD + h;

  __shared__ short Ks[2][64 * 64];
  __shared__ short Vts[2][64 * 64];
  __shared__ short Ps[4][16 * 64];

  const int srow = t >> 3;
  const int scolb = ((t & 7) * 16) ^ ((srow & 7) << 4);  // pre-swizzled

  const int qt0 = p, qt1 = QT - 1 - p;
  const int T0 = qt0 + 1, total = T0 + qt1 + 1;

  int qt = qt0;
  const short* qr = Qb + (bh * SEQ + (size_t)qt0 * 64 + w * 16 + la) * 64;
  bf16x8 qf0 = *(const bf16x8*)(qr + g * 8);
  bf16x8 qf1 = *(const bf16x8*)(qr + 32 + g * 8);

  float o[16];
  #pragma unroll
  for (int i = 0; i < 16; ++i) o[i] = 0.f;
  float m = -1e30f, l = 0.f;

  // prologue: stage tile it=0 (k0=0) into buf 0
  #pragma unroll
  for (int i = 0; i < 2; ++i) {
    const int r = srow + i * 32;
    gl16(Kb + (bh * SEQ + r) * 64 + (scolb >> 1), Ks[0] + i * 2048 + t * 8);
    gl16(Vtb + (bh * 64 + r) * SEQ + (scolb >> 1), Vts[0] + i * 2048 + t * 8);
  }
  __syncthreads();  // vmcnt(0) drain: tile 0 resident

  int cur = 0;
  #pragma unroll 1
  for (int it = 0; it < total; ++it) {
    // issue next tile's staging early (hidden under QK/softmax/PV)
    if (it + 1 < total) {
      const int nkt = (it + 1 < T0) ? (it + 1) : (it + 1 - T0);
      const int nk0 = nkt * 64;
      #pragma unroll
      for (int i = 0; i < 2; ++i) {
        const int r = srow + i * 32;
        gl16(Kb + (bh * SEQ + nk0 + r) * 64 + (scolb >> 1),
             Ks[cur ^ 1] + i * 2048 + t * 8);
        gl16(Vtb + (bh * 64 + r) * SEQ + nk0 + (scolb >> 1),
             Vts[cur ^ 1] + i * 2048 + t * 8);
      }
    }

    // === QK^T on buf[cur] ===
    float sv[16];
    __builtin_amdgcn_s_setprio(1);
    #pragma unroll
    for (int mt = 0; mt < 4; ++mt) {
      const int ar = mt * 16 + la;
      const int ab = ar * 128 + ((g * 16) ^ ((ar & 7) << 4));
      bf16x8 ka0 = *(const bf16x8*)((char*)Ks[cur] + ab);
      bf16x8 ka1 = *(const bf16x8*)((char*)Ks[cur] + (ab ^ 64));
      f32x4 sa = {0.f, 0.f, 0.f, 0.f};
      sa = __builtin_amdgcn_mfma_f32_16x16x32_bf16(ka0, qf0, sa, 0, 0, 0);
      sa = __builtin_amdgcn_mfma_f32_16x16x32_bf16(ka1, qf1, sa, 0, 0, 0);
      sv[mt * 4 + 0] = sa[0]; sv[mt * 4 + 1] = sa[1];
      sv[mt * 4 + 2] = sa[2]; sv[mt * 4 + 3] = sa[3];
    }
    __builtin_amdgcn_s_setprio(0);

    const bool diag = (it == T0 - 1) || (it == total - 1);
    if (diag) {  // causal mask (log2 domain: -10000*log2e)
      const int qrel = w * 16 + la;
      #pragma unroll
      for (int idx = 0; idx < 16; ++idx) {
        const int krel = (idx >> 2) * 16 + g * 4 + (idx & 3);
        if (krel > qrel) sv[idx] = -14426.950408889634f;
      }
    }

    // tree max over 16, then cross-g (lanes share la -> per-q-row max)
    float t8[8], t4[4], t2[2];
    #pragma unroll
    for (int i = 0; i < 8; ++i) t8[i] = fmaxf(sv[2 * i], sv[2 * i + 1]);
    #pragma unroll
    for (int i = 0; i < 4; ++i) t4[i] = fmaxf(t8[2 * i], t8[2 * i + 1]);
    t2[0] = fmaxf(t4[0], t4[1]); t2[1] = fmaxf(t4[2], t4[3]);
    float tmax = fmaxf(t2[0], t2[1]);
    tmax = fmaxf(tmax, __shfl_xor(tmax, 16));
    tmax = fmaxf(tmax, __shfl_xor(tmax, 32));

    const bool skip = __all(tmax <= m + 11.5f) != 0;  // defer-max (T13)
    const float mn = skip ? m : fmaxf(m, tmax);

    float ss8[8], ss4[4];
    #pragma unroll
    for (int i = 0; i < 16; ++i) sv[i] = exp2f(sv[i] - mn);
    #pragma unroll
    for (int i = 0; i < 8; ++i) ss8[i] = sv[2 * i] + sv[2 * i + 1];
    #pragma unroll
    for (int i = 0; i < 4; ++i) ss4[i] = ss8[2 * i] + ss8[2 * i + 1];
    float ps = (ss4[0] + ss4[1]) + (ss4[2] + ss4[3]);
    ps += __shfl_xor(ps, 16);
    ps += __shfl_xor(ps, 32);

    if (skip) {
      l += ps;
    } else {
      const float sc = exp2f(m - mn);
      l = l * sc + ps;
      m = mn;
      #pragma unroll
      for (int r = 0; r < 4; ++r) {
        const float scr = __shfl(sc, (g << 2) + r);
        o[r] *= scr; o[4 + r] *= scr; o[8 + r] *= scr; o[12 + r] *= scr;
      }
    }

    // write P (bf16) to per-wave swizzled LDS
    #pragma unroll
    for (int mt = 0; mt < 4; ++mt) {
      #pragma unroll
      for (int r2 = 0; r2 < 2; ++r2) {
        const unsigned pk = (unsigned)f2b(sv[mt * 4 + r2 * 2]) |
                            ((unsigned)f2b(sv[mt * 4 + r2 * 2 + 1]) << 16);
        const int kk = mt * 16 + g * 4 + r2 * 2;
        const int pb = la * 128 + ((kk * 2) ^ ((la & 7) << 4));
        *(unsigned*)((char*)Ps[w] + pb) = pk;
      }
    }
    // same-wave cross-lane LDS RAW hazard: drain + pin (rule #18);
    // gl16 staging uses vmcnt, NOT lgkmcnt -> stays in flight.
    asm volatile("s_waitcnt lgkmcnt(0)" ::: "memory");
    __builtin_amdgcn_sched_barrier(0);

    const int pb0 = la * 128 + ((g * 16) ^ ((la & 7) << 4));
    const bf16x8 pa0 = *(const bf16x8*)((char*)Ps[w] + pb0);
    const bf16x8 pa1 = *(const bf16x8*)((char*)Ps[w] + (pb0 ^ 64));
    __builtin_amdgcn_s_setprio(1);
    #pragma unroll
    for (int nt = 0; nt < 4; ++nt) {
      const int dr = nt * 16 + la;
      const int vb = dr * 128 + ((g * 16) ^ ((dr & 7) << 4));
      bf16x8 vb0 = *(const bf16x8*)((char*)Vts[cur] + vb);
      bf16x8 vb1 = *(const bf16x8*)((char*)Vts[cur] + (vb ^ 64));
      f32x4 oa = {o[nt * 4 + 0], o[nt * 4 + 1], o[nt * 4 + 2], o[nt * 4 + 3]};
      oa = __builtin_amdgcn_mfma_f32_16x16x32_bf16(pa0, vb0, oa, 0, 0, 0);
      oa = __builtin_amdgcn_mfma_f32_16x16x32_bf16(pa1, vb1, oa, 0, 0, 0);
      o[nt * 4 + 0] = oa[0]; o[nt * 4 + 1] = oa[1];
      o[nt * 4 + 2] = oa[2]; o[nt * 4 + 3] = oa[3];
    }
    __builtin_amdgcn_s_setprio(0);

    if (diag) {  // finished a q-tile: write output (and reset for e=1)
      const float linv = 1.f / l;
      #pragma unroll
      for (int r = 0; r < 4; ++r) {
        const float li = __shfl(linv, (g << 2) + r);
        const int qrow_g = qt * 64 + w * 16 + g * 4 + r;
        #pragma unroll
        for (int nt = 0; nt < 4; ++nt) {
          out[((size_t)b * SEQ + qrow_g) * DMODEL + h * 64 + nt * 16 + la] =
              (short)f2b(o[nt * 4 + r] * li);
        }
      }
      if (it == T0 - 1) {
        #pragma unroll
        for (int i = 0; i < 16; ++i) o[i] = 0.f;
        m = -1e30f; l = 0.f;
        qt = qt1;
        const short* qr1 = Qb + (bh * SEQ + (size_t)qt1 * 64 + w * 16 + la) * 64;
        qf0 = *(const bf16x8*)(qr1 + g * 8);
        qf1 = *(const bf16x8*)(qr1 + 32 + g * 8);
      }
    }

    __syncthreads();  // vmcnt(0)+lgkmcnt(0): next tile resident, reads done
    cur ^= 1;
  }
}

// ---------------------------------------------------------------------------
// Launcher
// ---------------------------------------------------------------------------
extern "C" void kernel_launch(void* const* d_in, const int* in_sizes, int n_in,
                              void* d_out, int out_size, void* d_ws, size_t ws_size,
                              hipStream_t stream) {
  const float* hidden      = (const float*)d_in[0];
  const float* ln1_g       = (const float*)d_in[1];
  const float* ln1_b       = (const float*)d_in[2];
  const float* w_attn      = (const float*)d_in[3];
  const float* b_attn      = (const float*)d_in[4];
  const float* w_attn_proj = (const float*)d_in[5];
  const float* b_attn_proj = (const float*)d_in[6];
  const float* ln2_g       = (const float*)d_in[7];
  const float* ln2_b       = (const float*)d_in[8];
  const float* w_fc        = (const float*)d_in[9];
  const float* b_fc        = (const float*)d_in[10];
  const float* w_mlp_proj  = (const float*)d_in[11];
  const float* b_mlp_proj  = (const float*)d_in[12];
  float* out = (float*)d_out;

  const int Bn = in_sizes[0] / (SEQ * DMODEL);  // batch (=4)
  const int M = Bn * SEQ;                        // 8192 rows

  // Workspace layout (bytes, ~210MB):
  char* W = (char*)d_ws;
  const size_t szMD2 = (size_t)M * DMODEL * 2;        // 16.8MB
  short* xln_b  = (short*)W;                          // LN out
  short* Vb     = (short*)(W + szMD2);                // V [bh][s][64] (attn phase)
  short* a1_b   = Vb;                                 // later: FF acts [M,FF] bf16
  char*  p2     = W + szMD2 + (size_t)M * FFDIM * 2;
  short* Qb     = (short*)p2;
  short* Kb     = Qb + (size_t)M * DMODEL;
  short* Vtb    = Kb + (size_t)M * DMODEL;
  short* attn_b = Vtb + (size_t)M * DMODEL;
  float* h2     = (float*)(p2 + 4 * szMD2);
  short* wat    = (short*)(p2 + 4 * szMD2 + (size_t)M * DMODEL * 4);
  short* wpt    = wat + (size_t)3 * DMODEL * DMODEL;
  short* wft    = wpt + (size_t)DMODEL * DMODEL;
  short* wmt    = wft + (size_t)FFDIM * DMODEL;
  float* bas    = (float*)(wmt + (size_t)DMODEL * FFDIM);  // scaled b_attn

  // 0. fused weight convert+transpose (+ bias prescale block)
  wconv4_kernel<<<3073, 256, 0, stream>>>(w_attn, wat, w_attn_proj, wpt,
                                          w_fc, wft, w_mlp_proj, wmt,
                                          b_attn, bas);
  // 1. LN1 -> bf16
  ln_kernel<<<M, 256, 0, stream>>>(hidden, ln1_g, ln1_b, xln_b);
  // 2. QKV GEMM (1-D grid 24*64=1536), scatter epilogue (Q pre-scaled)
  gemm_bf16<true, false, false, true><<<24 * 64, 256, 0, stream>>>(
      xln_b, wat, bas, nullptr, Qb, Kb, Vb, M, 3 * DMODEL, DMODEL, 24);
  // 2.5 V transpose only
  prepv_kernel<<<dim3(SEQ / 64, NHEAD, Bn), 256, 0, stream>>>(Vb, Vtb);
  // 3. attention -> bf16 [M,1024]  (paired q-tiles, double-buffered)
  mha_kernel<<<dim3(QT / 2, NHEAD, Bn), 256, 0, stream>>>(Qb, Kb, Vtb, attn_b);
  // 4. h2 = hidden + attn @ w_attn_proj + b   (fp32; grid 8*64=512)
  gemm_bf16<false, false, true, false><<<8 * 64, 256, 0, stream>>>(
      attn_b, wpt, b_attn_proj, hidden, h2, nullptr, nullptr, M, DMODEL, DMODEL, 8);
  // 5. LN2 -> bf16
  ln_kernel<<<M, 256, 0, stream>>>(h2, ln2_g, ln2_b, xln_b);
  // 6. a1 = gelu(xln2 @ w_fc + b) -> bf16 [M,4096]  (grid 32*64=2048)
  gemm_bf16<true, true, false, false><<<32 * 64, 256, 0, stream>>>(
      xln_b, wft, b_fc, nullptr, a1_b, nullptr, nullptr, M, FFDIM, DMODEL, 32);
  // 7. out = h2 + a1 @ w_mlp_proj + b  (fp32; grid 8*64=512)
  gemm_bf16<false, false, true, false><<<8 * 64, 256, 0, stream>>>(
      a1_b, wmt, b_mlp_proj, h2, out, nullptr, nullptr, M, DMODEL, FFDIM, 8);
}

// Round 13
// 499.706 us; speedup vs baseline: 1.0648x; 1.0223x over previous
//
#include <hip/hip_runtime.h>
#include <hip/hip_bf16.h>
#include <cstddef>

// GPT-2 block. B=4 (derived), S=2048, D=1024, H=16, DH=64, FF=4096.
#define SEQ   2048
#define DMODEL 1024
#define NHEAD 16
#define HDIM  64
#define FFDIM 4096
#define QT    (SEQ / 64)   // 32 q-tiles

typedef __attribute__((ext_vector_type(8))) short bf16x8;
typedef __attribute__((ext_vector_type(4))) short bf16x4;
typedef __attribute__((ext_vector_type(4))) float f32x4;

#define QSCALE (0.125f * 1.44269504088896f)  // 1/sqrt(64) * log2(e)

__device__ __forceinline__ unsigned short f2b(float x) {
  __hip_bfloat16 h = __float2bfloat16(x);
  return __builtin_bit_cast(unsigned short, h);
}
__device__ __forceinline__ float b2f(short u) {
  unsigned x = ((unsigned)(unsigned short)u) << 16;
  return __builtin_bit_cast(float, x);
}
// async global->LDS, 16B per lane. LDS dest = wave-uniform base + lane*16.
__device__ __forceinline__ void gl16(const short* g, short* l) {
  __builtin_amdgcn_global_load_lds(
      (const __attribute__((address_space(1))) void*)g,
      (__attribute__((address_space(3))) void*)l, 16, 0, 0);
}

// ---------------------------------------------------------------------------
// LayerNorm: one block per row, 256 threads, float4/thread; bf16 output.
// ---------------------------------------------------------------------------
__global__ __launch_bounds__(256)
void ln_kernel(const float* __restrict__ x, const float* __restrict__ g,
               const float* __restrict__ b, short* __restrict__ y) {
  const int row = blockIdx.x;
  const int t = threadIdx.x;
  const float* xr = x + (size_t)row * DMODEL;
  float4 v = *(const float4*)(xr + t * 4);
  float s = v.x + v.y + v.z + v.w;
  float q = v.x * v.x + v.y * v.y + v.z * v.z + v.w * v.w;
  #pragma unroll
  for (int off = 32; off; off >>= 1) {
    s += __shfl_xor(s, off);
    q += __shfl_xor(q, off);
  }
  __shared__ float ss[4], qq[4];
  if ((t & 63) == 0) { ss[t >> 6] = s; qq[t >> 6] = q; }
  __syncthreads();
  s = ss[0] + ss[1] + ss[2] + ss[3];
  q = qq[0] + qq[1] + qq[2] + qq[3];
  const float mean = s * (1.f / DMODEL);
  const float var = q * (1.f / DMODEL) - mean * mean;
  const float rstd = rsqrtf(var + 1e-5f);
  float4 gv = *(const float4*)(g + t * 4);
  float4 bv = *(const float4*)(b + t * 4);
  bf16x4 o;
  o[0] = (short)f2b((v.x - mean) * rstd * gv.x + bv.x);
  o[1] = (short)f2b((v.y - mean) * rstd * gv.y + bv.y);
  o[2] = (short)f2b((v.z - mean) * rstd * gv.z + bv.z);
  o[3] = (short)f2b((v.w - mean) * rstd * gv.w + bv.w);
  *(bf16x4*)(y + (size_t)row * DMODEL + t * 4) = o;
}

// ---------------------------------------------------------------------------
// GELU (GPT-2 'gelu_new')
// ---------------------------------------------------------------------------
__device__ __forceinline__ float gelu_new_f(float x) {
  const float c = 0.7978845608028654f;  // sqrt(2/pi)
  float u = c * (x + 0.044715f * x * x * x);
  float e = __expf(2.f * u);
  float t = 1.f - 2.f / (e + 1.f);
  return 0.5f * x * (1.f + t);
}

// ---------------------------------------------------------------------------
// Fused weight convert+transpose (fp32 [K][N] -> bf16 [N][K]) for 4 weights.
// Q-columns (n<1024) of w_attn pre-scaled by QSCALE. Block 3072 scales b_attn.
// ---------------------------------------------------------------------------
__global__ __launch_bounds__(256)
void wconv4_kernel(const float* __restrict__ w0, short* __restrict__ t0,
                   const float* __restrict__ w1, short* __restrict__ t1,
                   const float* __restrict__ w2, short* __restrict__ t2,
                   const float* __restrict__ w3, short* __restrict__ t3,
                   const float* __restrict__ ba, float* __restrict__ bas) {
  int id = blockIdx.x;
  const int t = threadIdx.x;
  if (id == 3072) {  // bias pre-scale for the QKV GEMM
    #pragma unroll
    for (int i = t; i < 3072; i += 256)
      bas[i] = ba[i] * (i < 1024 ? QSCALE : 1.f);
    return;
  }
  const float* W; short* Wt; int K, N;
  float sc = 1.f;
  if (id < 768)       { W = w0; Wt = t0; K = 1024; N = 3072; }
  else if (id < 1024) { id -= 768;  W = w1; Wt = t1; K = 1024; N = 1024; }
  else if (id < 2048) { id -= 1024; W = w2; Wt = t2; K = 1024; N = 4096; }
  else                { id -= 2048; W = w3; Wt = t3; K = 4096; N = 1024; }
  const int nt = N >> 6;
  const int n0 = (id % nt) * 64, k0 = (id / nt) * 64;
  if (W == w0 && n0 < 1024) sc = QSCALE;  // Q column block
  __shared__ short tile[64][72];
  #pragma unroll
  for (int i = 0; i < 4; ++i) {
    const int row = i * 16 + (t >> 4);      // k within tile
    const int col4 = (t & 15) * 4;          // n within tile
    float4 v = *(const float4*)(W + (size_t)(k0 + row) * N + n0 + col4);
    tile[col4 + 0][row] = (short)f2b(v.x * sc);
    tile[col4 + 1][row] = (short)f2b(v.y * sc);
    tile[col4 + 2][row] = (short)f2b(v.z * sc);
    tile[col4 + 3][row] = (short)f2b(v.w * sc);
  }
  __syncthreads();
  #pragma unroll
  for (int i = 0; i < 2; ++i) {
    const int cc = t + i * 256;
    const int nr = cc >> 3, k8 = (cc & 7) * 8;
    bf16x8 vv;
    #pragma unroll
    for (int j = 0; j < 8; ++j) vv[j] = tile[nr][k8 + j];
    *(bf16x8*)(Wt + (size_t)(n0 + nr) * K + k0 + k8) = vv;
  }
}

// ---------------------------------------------------------------------------
// bf16 MFMA GEMM (validated R10): 128x128 tile, BK=64, 4 waves,
// counted-vmcnt 2-buffer pipeline, XCD swizzle, setprio.
// ---------------------------------------------------------------------------
template <bool OUTBF, bool GELU, bool RES, bool QKVS>
__global__ __launch_bounds__(256)
void gemm_bf16(const short* __restrict__ A, const short* __restrict__ Bt,
               const float* __restrict__ bias, const float* __restrict__ R,
               void* __restrict__ C, short* __restrict__ C2,
               short* __restrict__ C3, int M, int N, int K, int nbn) {
  __shared__ short As[2][128 * 64];
  __shared__ short Bs[2][128 * 64];
  const int t = threadIdx.x, lane = t & 63, w = t >> 6;
  const int g = lane >> 4, la = lane & 15;
  // XCD swizzle: consecutive swz ids land on one XCD -> A-panel L2 locality
  const int cpx = gridDim.x >> 3;
  const int swz = (blockIdx.x & 7) * cpx + (blockIdx.x >> 3);
  const int bn = swz % nbn, bm = swz / nbn;
  const int wm = w >> 1, wn = w & 1;

  const int srow = t >> 3;
  const int scolb = ((t & 7) * 16) ^ ((srow & 7) << 4);  // pre-swizzled byte col
  const short* Ag = A + (size_t)(bm * 128 + srow) * K + (scolb >> 1);
  const short* Bg = Bt + (size_t)(bn * 128 + srow) * K + (scolb >> 1);

  f32x4 acc[4][4];
  #pragma unroll
  for (int i = 0; i < 4; ++i)
    #pragma unroll
    for (int j = 0; j < 4; ++j) acc[i][j] = (f32x4){0.f, 0.f, 0.f, 0.f};

  const int KT = K >> 6;
  #define STAGE_G(buf, kt)                                                  \
    do {                                                                    \
      _Pragma("unroll")                                                     \
      for (int i = 0; i < 4; ++i) {                                         \
        gl16(Ag + (size_t)i * 32 * K + (kt) * 64, As[buf] + i * 2048 + t * 8); \
        gl16(Bg + (size_t)i * 32 * K + (kt) * 64, Bs[buf] + i * 2048 + t * 8); \
      }                                                                     \
    } while (0)

  // prologue: 16 loads in flight (T0: 8 older, T1: 8 newer)
  STAGE_G(0, 0);
  STAGE_G(1, 1);

  int cur = 0;
  #pragma unroll 1
  for (int kt = 0; kt < KT; ++kt) {
    // T_kt resident (own 8 oldest), T_{kt+1} stays in flight across barrier
    if (kt + 1 < KT) {
      asm volatile("s_waitcnt vmcnt(8)\n\ts_barrier" ::: "memory");
    } else {
      asm volatile("s_waitcnt vmcnt(0)\n\ts_barrier" ::: "memory");
    }
    __builtin_amdgcn_sched_barrier(0);

    bf16x8 af[4], bfr[4];
    #pragma unroll
    for (int ks = 0; ks < 2; ++ks) {
      #pragma unroll
      for (int mi = 0; mi < 4; ++mi) {
        const int row = wm * 64 + mi * 16 + la;
        af[mi] = *(const bf16x8*)((const char*)As[cur] + row * 128 +
                                  ((ks * 64 + g * 16) ^ ((row & 7) << 4)));
      }
      #pragma unroll
      for (int ni = 0; ni < 4; ++ni) {
        const int row = wn * 64 + ni * 16 + la;
        bfr[ni] = *(const bf16x8*)((const char*)Bs[cur] + row * 128 +
                                   ((ks * 64 + g * 16) ^ ((row & 7) << 4)));
      }
      __builtin_amdgcn_s_setprio(1);
      #pragma unroll
      for (int mi = 0; mi < 4; ++mi)
        #pragma unroll
        for (int ni = 0; ni < 4; ++ni)
          acc[mi][ni] = __builtin_amdgcn_mfma_f32_16x16x32_bf16(
              af[mi], bfr[ni], acc[mi][ni], 0, 0, 0);
      __builtin_amdgcn_s_setprio(0);
    }

    // all waves' ds_reads of buf[cur] complete -> safe to restage into it
    asm volatile("s_barrier" ::: "memory");
    __builtin_amdgcn_sched_barrier(0);
    if (kt + 2 < KT) STAGE_G(cur, kt + 2);
    cur ^= 1;
  }
  #undef STAGE_G

  const int crow0 = bm * 128 + wm * 64 + g * 4;
  const int ccol0 = bn * 128 + wn * 64 + la;
  float bl[4];
  #pragma unroll
  for (int ni = 0; ni < 4; ++ni) bl[ni] = bias[ccol0 + ni * 16];
  #pragma unroll
  for (int mi = 0; mi < 4; ++mi) {
    #pragma unroll
    for (int r = 0; r < 4; ++r) {
      const int row = crow0 + mi * 16 + r;
      if (QKVS) {
        const int bq = row >> 11, s = row & 2047;   // SEQ=2048
        #pragma unroll
        for (int ni = 0; ni < 4; ++ni) {
          const int n = ccol0 + ni * 16;
          const int region = n >> 10;               // 0=Q 1=K 2=V
          const int nn = n & 1023;
          short* dst = region == 0 ? (short*)C : (region == 1 ? C2 : C3);
          dst[((size_t)(bq * NHEAD + (nn >> 6)) * SEQ + s) * 64 + (nn & 63)] =
              (short)f2b(acc[mi][ni][r] + bl[ni]);
        }
      } else {
        #pragma unroll
        for (int ni = 0; ni < 4; ++ni) {
          float v = acc[mi][ni][r] + bl[ni];
          if (GELU) v = gelu_new_f(v);
          if (RES) v += R[(size_t)row * N + ccol0 + ni * 16];
          if (OUTBF)
            ((short*)C)[(size_t)row * N + ccol0 + ni * 16] = (short)f2b(v);
          else
            ((float*)C)[(size_t)row * N + ccol0 + ni * 16] = v;
        }
      }
    }
  }
}

// ---------------------------------------------------------------------------
// V transpose: Vb bf16 [b][h][s][64] -> Vtb bf16 [b][h][64][s] (LDS tile).
// ---------------------------------------------------------------------------
__global__ __launch_bounds__(256)
void prepv_kernel(const short* __restrict__ Vb, short* __restrict__ Vtb) {
  const int st = blockIdx.x, h = blockIdx.y, b = blockIdx.z;
  const int t = threadIdx.x;
  const int s0 = st * 64;
  const size_t bh = (size_t)b * NHEAD + h;
  __shared__ short vt[64][72];
  #pragma unroll
  for (int i = 0; i < 2; ++i) {
    const int cc = t + i * 256;
    const int r = cc >> 3, d8 = (cc & 7) * 8;
    bf16x8 v8 = *(const bf16x8*)(Vb + (bh * SEQ + s0 + r) * 64 + d8);
    #pragma unroll
    for (int j = 0; j < 8; ++j) vt[d8 + j][r] = v8[j];
  }
  __syncthreads();
  #pragma unroll
  for (int i = 0; i < 2; ++i) {
    const int cc = t + i * 256;
    const int d = cc >> 3, s8 = (cc & 7) * 8;
    bf16x8 vv;
    #pragma unroll
    for (int j = 0; j < 8; ++j) vv[j] = vt[d][s8 + j];
    *(bf16x8*)(Vtb + (bh * 64 + d) * SEQ + s0 + s8) = vv;
  }
}

// ---------------------------------------------------------------------------
// bf16 MFMA causal flash attention (validated R7-R10): paired q-tiles,
// double-buffered staging, log2-domain softmax, defer-max, setprio.
// NEW (R11): 1-D grid 1024 with chunked XCD swizzle — each XCD owns 8
// whole (b,h) groups => its K/V working set = 8 x 512KB = 4MB = one L2.
// Was p-major: all 8 XCDs read the SAME head simultaneously into 8 L2s
// and each XCD eventually touched all 64 heads (FETCH 252MB vs 33.5MB K/V).
// Max-reduce via v_max3 chains (T17).
// ---------------------------------------------------------------------------
__global__ __launch_bounds__(256)
void mha_kernel(const short* __restrict__ Qb, const short* __restrict__ Kb,
                const short* __restrict__ Vtb, short* __restrict__ out) {
  // chunked XCD swizzle: bid%8 = XCD -> swz contiguous per XCD
  const int swz = (blockIdx.x & 7) * (QT / 2 * NHEAD * 4 / 8) + (blockIdx.x >> 3);
  const int p = swz & (QT / 2 - 1);          // 16 pairs per bh
  const int bh_i = swz >> 4;                 // 0..63
  const int h = bh_i & (NHEAD - 1), b = bh_i >> 4;
  const int t = threadIdx.x, lane = t & 63, w = t >> 6;
  const int g = lane >> 4, la = lane & 15;
  const size_t bh = (size_t)b * NHEAD + h;

  __shared__ short Ks[2][64 * 64];
  __shared__ short Vts[2][64 * 64];
  __shared__ short Ps[4][16 * 64];

  const int srow = t >> 3;
  const int scolb = ((t & 7) * 16) ^ ((srow & 7) << 4);  // pre-swizzled

  const int qt0 = p, qt1 = QT - 1 - p;
  const int T0 = qt0 + 1, total = T0 + qt1 + 1;

  int qt = qt0;
  const short* qr = Qb + (bh * SEQ + (size_t)qt0 * 64 + w * 16 + la) * 64;
  bf16x8 qf0 = *(const bf16x8*)(qr + g * 8);
  bf16x8 qf1 = *(const bf16x8*)(qr + 32 + g * 8);

  float o[16];
  #pragma unroll
  for (int i = 0; i < 16; ++i) o[i] = 0.f;
  float m = -1e30f, l = 0.f;

  // prologue: stage tile it=0 (k0=0) into buf 0
  #pragma unroll
  for (int i = 0; i < 2; ++i) {
    const int r = srow + i * 32;
    gl16(Kb + (bh * SEQ + r) * 64 + (scolb >> 1), Ks[0] + i * 2048 + t * 8);
    gl16(Vtb + (bh * 64 + r) * SEQ + (scolb >> 1), Vts[0] + i * 2048 + t * 8);
  }
  __syncthreads();  // vmcnt(0) drain: tile 0 resident

  int cur = 0;
  #pragma unroll 1
  for (int it = 0; it < total; ++it) {
    // issue next tile's staging early (hidden under QK/softmax/PV)
    if (it + 1 < total) {
      const int nkt = (it + 1 < T0) ? (it + 1) : (it + 1 - T0);
      const int nk0 = nkt * 64;
      #pragma unroll
      for (int i = 0; i < 2; ++i) {
        const int r = srow + i * 32;
        gl16(Kb + (bh * SEQ + nk0 + r) * 64 + (scolb >> 1),
             Ks[cur ^ 1] + i * 2048 + t * 8);
        gl16(Vtb + (bh * 64 + r) * SEQ + nk0 + (scolb >> 1),
             Vts[cur ^ 1] + i * 2048 + t * 8);
      }
    }

    // === QK^T on buf[cur] ===
    float sv[16];
    __builtin_amdgcn_s_setprio(1);
    #pragma unroll
    for (int mt = 0; mt < 4; ++mt) {
      const int ar = mt * 16 + la;
      const int ab = ar * 128 + ((g * 16) ^ ((ar & 7) << 4));
      bf16x8 ka0 = *(const bf16x8*)((char*)Ks[cur] + ab);
      bf16x8 ka1 = *(const bf16x8*)((char*)Ks[cur] + (ab ^ 64));
      f32x4 sa = {0.f, 0.f, 0.f, 0.f};
      sa = __builtin_amdgcn_mfma_f32_16x16x32_bf16(ka0, qf0, sa, 0, 0, 0);
      sa = __builtin_amdgcn_mfma_f32_16x16x32_bf16(ka1, qf1, sa, 0, 0, 0);
      sv[mt * 4 + 0] = sa[0]; sv[mt * 4 + 1] = sa[1];
      sv[mt * 4 + 2] = sa[2]; sv[mt * 4 + 3] = sa[3];
    }
    __builtin_amdgcn_s_setprio(0);

    const bool diag = (it == T0 - 1) || (it == total - 1);
    if (diag) {  // causal mask (log2 domain: -10000*log2e)
      const int qrel = w * 16 + la;
      #pragma unroll
      for (int idx = 0; idx < 16; ++idx) {
        const int krel = (idx >> 2) * 16 + g * 4 + (idx & 3);
        if (krel > qrel) sv[idx] = -14426.950408889634f;
      }
    }

    // max over 16 via v_max3 chains (T17), then cross-g shuffles
    float m0 = fmaxf(fmaxf(sv[0], sv[1]), sv[2]);
    float m1 = fmaxf(fmaxf(sv[3], sv[4]), sv[5]);
    float m2 = fmaxf(fmaxf(sv[6], sv[7]), sv[8]);
    float m3 = fmaxf(fmaxf(sv[9], sv[10]), sv[11]);
    float m4 = fmaxf(fmaxf(sv[12], sv[13]), sv[14]);
    float tmax = fmaxf(fmaxf(fmaxf(m0, m1), m2),
                       fmaxf(fmaxf(m3, m4), sv[15]));
    tmax = fmaxf(tmax, __shfl_xor(tmax, 16));
    tmax = fmaxf(tmax, __shfl_xor(tmax, 32));

    const bool skip = __all(tmax <= m + 11.5f) != 0;  // defer-max (T13)
    const float mn = skip ? m : fmaxf(m, tmax);

    float ss8[8], ss4[4];
    #pragma unroll
    for (int i = 0; i < 16; ++i) sv[i] = exp2f(sv[i] - mn);
    #pragma unroll
    for (int i = 0; i < 8; ++i) ss8[i] = sv[2 * i] + sv[2 * i + 1];
    #pragma unroll
    for (int i = 0; i < 4; ++i) ss4[i] = ss8[2 * i] + ss8[2 * i + 1];
    float ps = (ss4[0] + ss4[1]) + (ss4[2] + ss4[3]);
    ps += __shfl_xor(ps, 16);
    ps += __shfl_xor(ps, 32);

    if (skip) {
      l += ps;
    } else {
      const float sc = exp2f(m - mn);
      l = l * sc + ps;
      m = mn;
      #pragma unroll
      for (int r = 0; r < 4; ++r) {
        const float scr = __shfl(sc, (g << 2) + r);
        o[r] *= scr; o[4 + r] *= scr; o[8 + r] *= scr; o[12 + r] *= scr;
      }
    }

    // write P (bf16) to per-wave swizzled LDS
    #pragma unroll
    for (int mt = 0; mt < 4; ++mt) {
      #pragma unroll
      for (int r2 = 0; r2 < 2; ++r2) {
        const unsigned pk = (unsigned)f2b(sv[mt * 4 + r2 * 2]) |
                            ((unsigned)f2b(sv[mt * 4 + r2 * 2 + 1]) << 16);
        const int kk = mt * 16 + g * 4 + r2 * 2;
        const int pb = la * 128 + ((kk * 2) ^ ((la & 7) << 4));
        *(unsigned*)((char*)Ps[w] + pb) = pk;
      }
    }
    // same-wave cross-lane LDS RAW hazard: drain + pin (rule #18);
    // gl16 staging uses vmcnt, NOT lgkmcnt -> stays in flight.
    asm volatile("s_waitcnt lgkmcnt(0)" ::: "memory");
    __builtin_amdgcn_sched_barrier(0);

    const int pb0 = la * 128 + ((g * 16) ^ ((la & 7) << 4));
    const bf16x8 pa0 = *(const bf16x8*)((char*)Ps[w] + pb0);
    const bf16x8 pa1 = *(const bf16x8*)((char*)Ps[w] + (pb0 ^ 64));
    __builtin_amdgcn_s_setprio(1);
    #pragma unroll
    for (int nt = 0; nt < 4; ++nt) {
      const int dr = nt * 16 + la;
      const int vb = dr * 128 + ((g * 16) ^ ((dr & 7) << 4));
      bf16x8 vb0 = *(const bf16x8*)((char*)Vts[cur] + vb);
      bf16x8 vb1 = *(const bf16x8*)((char*)Vts[cur] + (vb ^ 64));
      f32x4 oa = {o[nt * 4 + 0], o[nt * 4 + 1], o[nt * 4 + 2], o[nt * 4 + 3]};
      oa = __builtin_amdgcn_mfma_f32_16x16x32_bf16(pa0, vb0, oa, 0, 0, 0);
      oa = __builtin_amdgcn_mfma_f32_16x16x32_bf16(pa1, vb1, oa, 0, 0, 0);
      o[nt * 4 + 0] = oa[0]; o[nt * 4 + 1] = oa[1];
      o[nt * 4 + 2] = oa[2]; o[nt * 4 + 3] = oa[3];
    }
    __builtin_amdgcn_s_setprio(0);

    if (diag) {  // finished a q-tile: write output (and reset for e=1)
      const float linv = 1.f / l;
      #pragma unroll
      for (int r = 0; r < 4; ++r) {
        const float li = __shfl(linv, (g << 2) + r);
        const int qrow_g = qt * 64 + w * 16 + g * 4 + r;
        #pragma unroll
        for (int nt = 0; nt < 4; ++nt) {
          out[((size_t)b * SEQ + qrow_g) * DMODEL + h * 64 + nt * 16 + la] =
              (short)f2b(o[nt * 4 + r] * li);
        }
      }
      if (it == T0 - 1) {
        #pragma unroll
        for (int i = 0; i < 16; ++i) o[i] = 0.f;
        m = -1e30f; l = 0.f;
        qt = qt1;
        const short* qr1 = Qb + (bh * SEQ + (size_t)qt1 * 64 + w * 16 + la) * 64;
        qf0 = *(const bf16x8*)(qr1 + g * 8);
        qf1 = *(const bf16x8*)(qr1 + 32 + g * 8);
      }
    }

    __syncthreads();  // vmcnt(0)+lgkmcnt(0): next tile resident, reads done
    cur ^= 1;
  }
}

// ---------------------------------------------------------------------------
// Launcher
// ---------------------------------------------------------------------------
extern "C" void kernel_launch(void* const* d_in, const int* in_sizes, int n_in,
                              void* d_out, int out_size, void* d_ws, size_t ws_size,
                              hipStream_t stream) {
  const float* hidden      = (const float*)d_in[0];
  const float* ln1_g       = (const float*)d_in[1];
  const float* ln1_b       = (const float*)d_in[2];
  const float* w_attn      = (const float*)d_in[3];
  const float* b_attn      = (const float*)d_in[4];
  const float* w_attn_proj = (const float*)d_in[5];
  const float* b_attn_proj = (const float*)d_in[6];
  const float* ln2_g       = (const float*)d_in[7];
  const float* ln2_b       = (const float*)d_in[8];
  const float* w_fc        = (const float*)d_in[9];
  const float* b_fc        = (const float*)d_in[10];
  const float* w_mlp_proj  = (const float*)d_in[11];
  const float* b_mlp_proj  = (const float*)d_in[12];
  float* out = (float*)d_out;

  const int Bn = in_sizes[0] / (SEQ * DMODEL);  // batch (=4)
  const int M = Bn * SEQ;                        // 8192 rows

  // Workspace layout (bytes, ~210MB):
  char* W = (char*)d_ws;
  const size_t szMD2 = (size_t)M * DMODEL * 2;        // 16.8MB
  short* xln_b  = (short*)W;                          // LN out
  short* Vb     = (short*)(W + szMD2);                // V [bh][s][64] (attn phase)
  short* a1_b   = Vb;                                 // later: FF acts [M,FF] bf16
  char*  p2     = W + szMD2 + (size_t)M * FFDIM * 2;
  short* Qb     = (short*)p2;
  short* Kb     = Qb + (size_t)M * DMODEL;
  short* Vtb    = Kb + (size_t)M * DMODEL;
  short* attn_b = Vtb + (size_t)M * DMODEL;
  float* h2     = (float*)(p2 + 4 * szMD2);
  short* wat    = (short*)(p2 + 4 * szMD2 + (size_t)M * DMODEL * 4);
  short* wpt    = wat + (size_t)3 * DMODEL * DMODEL;
  short* wft    = wpt + (size_t)DMODEL * DMODEL;
  short* wmt    = wft + (size_t)FFDIM * DMODEL;
  float* bas    = (float*)(wmt + (size_t)DMODEL * FFDIM);  // scaled b_attn

  // 0. fused weight convert+transpose (+ bias prescale block)
  wconv4_kernel<<<3073, 256, 0, stream>>>(w_attn, wat, w_attn_proj, wpt,
                                          w_fc, wft, w_mlp_proj, wmt,
                                          b_attn, bas);
  // 1. LN1 -> bf16
  ln_kernel<<<M, 256, 0, stream>>>(hidden, ln1_g, ln1_b, xln_b);
  // 2. QKV GEMM (1-D grid 24*64=1536), scatter epilogue (Q pre-scaled)
  gemm_bf16<true, false, false, true><<<24 * 64, 256, 0, stream>>>(
      xln_b, wat, bas, nullptr, Qb, Kb, Vb, M, 3 * DMODEL, DMODEL, 24);
  // 2.5 V transpose only
  prepv_kernel<<<dim3(SEQ / 64, NHEAD, Bn), 256, 0, stream>>>(Vb, Vtb);
  // 3. attention -> bf16 [M,1024]  (1-D grid, chunked XCD swizzle)
  mha_kernel<<<QT / 2 * NHEAD * Bn, 256, 0, stream>>>(Qb, Kb, Vtb, attn_b);
  // 4. h2 = hidden + attn @ w_attn_proj + b   (fp32; grid 8*64=512)
  gemm_bf16<false, false, true, false><<<8 * 64, 256, 0, stream>>>(
      attn_b, wpt, b_attn_proj, hidden, h2, nullptr, nullptr, M, DMODEL, DMODEL, 8);
  // 5. LN2 -> bf16
  ln_kernel<<<M, 256, 0, stream>>>(h2, ln2_g, ln2_b, xln_b);
  // 6. a1 = gelu(xln2 @ w_fc + b) -> bf16 [M,4096]  (grid 32*64=2048)
  gemm_bf16<true, true, false, false><<<32 * 64, 256, 0, stream>>>(
      xln_b, wft, b_fc, nullptr, a1_b, nullptr, nullptr, M, FFDIM, DMODEL, 32);
  // 7. out = h2 + a1 @ w_mlp_proj + b  (fp32; grid 8*64=512)
  gemm_bf16<false, false, true, false><<<8 * 64, 256, 0, stream>>>(
      a1_b, wmt, b_mlp_proj, h2, out, nullptr, nullptr, M, DMODEL, FFDIM, 8);
}